// Round 9
// baseline (491.670 us; speedup 1.0000x reference)
//
#include <hip/hip_runtime.h>
#include <hip/hip_bf16.h>

// EdgeProposer: probs/directions/relations heads over gathered belief pairs.
// f32 in / f32 out. Best: R6 196us (LDS-staged 128-row, B-outer, 2 barriers).
// Spill law (R5/R7/R8): acc[5][8]=160 regs => K-loop extras must be <=~50.
// R9: single-barrier DMA pipeline. LDS double-buffer holds ONLY src/tgt
// fragment tiles (2x32KB), staged by global_load_lds (zero staging regs);
// abs-seg A-fragments computed in-register during the MFMA phase. One
// barrier per k0-iter: its implicit vmcnt(0) drains the DMA issued one
// full MFMA phase (240 MFMAs) earlier -> gather latency hidden.

#define DD 512
#define K3 1536
#define ROWS 128
#define LDACT 328   // 320 + 8 pad
#define LDH 72
#define BUFS 16384  // shorts per buffer: 2 st * 2 kk2 * 8 rt * 64 lane * 8

typedef short bf16x8 __attribute__((ext_vector_type(8)));
typedef float f32x4 __attribute__((ext_vector_type(4)));

__device__ inline float b2f(short s) {
    union { float f; unsigned u; } v;
    v.u = ((unsigned)(unsigned short)s) << 16;
    return v.f;
}
__device__ inline short f2b(float f) {   // RNE
    union { float fl; unsigned u; } v;
    v.fl = f;
    unsigned x = v.u;
    unsigned r = x + 0x7fffu + ((x >> 16) & 1u);
    return (short)(r >> 16);
}
__device__ inline short babsdiff(short a, short b) {
    union { float f; unsigned u; } v;
    v.f = b2f(a) - b2f(b);
    return (short)((v.u & 0x7fffffffu) >> 16);
}

// buffer-local fragment index: [st][kk2][rt] block of 64 lanes x 8 shorts
__device__ __forceinline__ int sidx2(int st, int kk2, int rt, int lane) {
    return (((st * 2 + kk2) * 8 + rt) * 64 + lane) * 8;
}

// ---- workspace layout (shorts) ----
#define WT_ELEMS (320 * 1536)
#define P2T_OFF WT_ELEMS
#define R2T_OFF (WT_ELEMS + 64 * 128)
#define PREP_TOT (WT_ELEMS + 2 * 64 * 128)
#define BEL_ELEMS (8192 * 512)
#define BEL_OFF PREP_TOT

#define TRANS_BLOCKS 480   // (1536/32) * (320/32)
#define ELEM_TOT (2 * 64 * 128 + BEL_ELEMS)

__global__ void prep_kernel(const float* __restrict__ pw1,
                            const float* __restrict__ dw1,
                            const float* __restrict__ rw1,
                            const float* __restrict__ pw2,
                            const float* __restrict__ rw2,
                            const float* __restrict__ beliefs,
                            short* __restrict__ ws) {
    const int bx = blockIdx.x, t = threadIdx.x;
    if (bx < TRANS_BLOCKS) {
        __shared__ short tile[32][33];
        const int tk = (bx / 10) * 32, tn = (bx % 10) * 32;
        const int r = t >> 5, c = t & 31;
#pragma unroll
        for (int p = 0; p < 4; p++) {
            int k = tk + r + p * 8, n = tn + c;
            float v;
            if (n < 128)      v = pw1[k * 128 + n];
            else if (n < 192) v = dw1[k * 64 + (n - 128)];
            else              v = rw1[k * 128 + (n - 192)];
            tile[r + p * 8][c] = f2b(v);
        }
        __syncthreads();
#pragma unroll
        for (int p = 0; p < 4; p++) {
            int nn = tn + r + p * 8, kk = tk + c;
            ws[(size_t)nn * K3 + kk] = tile[c][r + p * 8];
        }
    } else {
        int j = (bx - TRANS_BLOCKS) * 256 + t;
        if (j >= ELEM_TOT) return;
        if (j < 8192) {
            int n = j >> 7, k = j & 127;
            ws[P2T_OFF + j] = f2b(pw2[k * 64 + n]);
        } else if (j < 16384) {
            int jj = j - 8192;
            int n = jj >> 7, k = jj & 127;
            ws[R2T_OFF + jj] = f2b(rw2[k * 64 + n]);
        } else {
            int idx = j - 16384;
            ws[BEL_OFF + idx] = f2b(beliefs[idx]);
        }
    }
}

// ---- main fused kernel: 128 pairs per block, 256 threads (4 waves) ----
template<bool BF>
__global__ __launch_bounds__(256, 2) void edge_main(
    const float* __restrict__ beliefs, const short* __restrict__ bel16,
    const int* __restrict__ src_idx, const int* __restrict__ tgt_idx,
    const float* __restrict__ pb1, const float* __restrict__ db1,
    const float* __restrict__ rb1,
    const float* __restrict__ pb2, const float* __restrict__ pw3,
    const float* __restrict__ pb3,
    const float* __restrict__ dw2, const float* __restrict__ db2,
    const float* __restrict__ rb2,
    const short* __restrict__ WT, const short* __restrict__ pw2T,
    const short* __restrict__ rw2T,
    float* __restrict__ out, int N)
{
    // two 32KB s/t fragment buffers (65536 B); epilogue aliases (51200 B).
    __shared__ __align__(16) short smem[2 * BUFS];
    __shared__ int sIdx[ROWS], tIdx[ROWS];
    short (*acts)[LDACT] = (short (*)[LDACT])smem;
    short (*h2s)[LDH] = (short (*)[LDH])(smem + 64 * LDACT);

    const int t = threadIdx.x;
    const int r0 = blockIdx.x * ROWS;
    const int w = t >> 6, lane = t & 63, q = lane >> 4, ln = lane & 15;

    if (t < ROWS) sIdx[t] = src_idx[r0 + t] * DD;
    else tIdx[t - ROWS] = tgt_idx[r0 + t - ROWS] * DD;
    __syncthreads();

    f32x4 acc[5][8];
#pragma unroll
    for (int ct = 0; ct < 5; ct++)
#pragma unroll
        for (int rt = 0; rt < 8; rt++) acc[ct][rt] = (f32x4)(0.f);

    // DMA staging role: wave w -> st = w>>1 (0=src,1=tgt), kk2 = w&1.
    const int stw = w >> 1, kk2w = w & 1;
    int preoff[8];
#pragma unroll
    for (int i = 0; i < 8; i++) {
        int row = i * 16 + ln;
        preoff[i] = (stw ? tIdx[row] : sIdx[row]) + kk2w * 32 + q * 8;
    }
    const int dmabase = sidx2(stw, kk2w, 0, 0);

    // f32 fallback staging role (thread-pair per row, R6 pattern)
    const int rrow = t >> 1, kk2p = t & 1;
    const int rtp = rrow >> 4, lnp = rrow & 15;
    const int srowF = sIdx[rrow], trowF = tIdx[rrow];

    const short* wtb = WT + (size_t)(w * 80 + ln) * K3 + q * 8;

#define STAGE(buf, kc)                                                        \
    do {                                                                      \
        if constexpr (BF) {                                                   \
            _Pragma("unroll")                                                 \
            for (int i = 0; i < 8; i++) {                                     \
                const short* gp = bel16 + preoff[i] + (kc);                   \
                short* lp = smem + (buf) * BUFS + dmabase + i * 512;          \
                __builtin_amdgcn_global_load_lds(                             \
                    (const __attribute__((address_space(1))) unsigned int*)gp,\
                    (__attribute__((address_space(3))) unsigned int*)lp,      \
                    16, 0, 0);                                                \
            }                                                                 \
        } else {                                                              \
            const float4* ps_ = (const float4*)(beliefs + srowF + (kc) + kk2p * 32); \
            const float4* pt_ = (const float4*)(beliefs + trowF + (kc) + kk2p * 32); \
            _Pragma("unroll")                                                 \
            for (int c = 0; c < 4; c++) {                                     \
                bf16x8 sb, tb;                                                \
                _Pragma("unroll")                                             \
                for (int hh = 0; hh < 2; hh++) {                              \
                    float4 s4 = ps_[c * 2 + hh], t4 = pt_[c * 2 + hh];        \
                    float ss[4] = {s4.x, s4.y, s4.z, s4.w};                   \
                    float tt[4] = {t4.x, t4.y, t4.z, t4.w};                   \
                    _Pragma("unroll")                                         \
                    for (int e = 0; e < 4; e++) {                             \
                        sb[hh * 4 + e] = f2b(ss[e]);                          \
                        tb[hh * 4 + e] = f2b(tt[e]);                          \
                    }                                                         \
                }                                                             \
                int l64 = c * 16 + lnp;                                       \
                *(bf16x8*)&smem[(buf) * BUFS + sidx2(0, kk2p, rtp, l64)] = sb;\
                *(bf16x8*)&smem[(buf) * BUFS + sidx2(1, kk2p, rtp, l64)] = tb;\
            }                                                                 \
        }                                                                     \
    } while (0)

    STAGE(0, 0);
    __syncthreads();

    for (int k0 = 0; k0 < DD; k0 += 64) {
        const int cur = (k0 >> 6) & 1;
        if (k0 + 64 < DD) STAGE(cur ^ 1, k0 + 64);

        const short* bufc = smem + cur * BUFS;
#pragma unroll
        for (int kk2 = 0; kk2 < 2; kk2++) {
            // seg0: src
            {
                bf16x8 bfr[5];
#pragma unroll
                for (int ct = 0; ct < 5; ct++)
                    bfr[ct] = *(const bf16x8*)(wtb + (size_t)ct * 16 * K3 +
                                               k0 + kk2 * 32);
#pragma unroll
                for (int rt = 0; rt < 8; rt++) {
                    bf16x8 af = *(const bf16x8*)&bufc[sidx2(0, kk2, rt, lane)];
#pragma unroll
                    for (int ct = 0; ct < 5; ct++)
                        acc[ct][rt] = __builtin_amdgcn_mfma_f32_16x16x32_bf16(
                            af, bfr[ct], acc[ct][rt], 0, 0, 0);
                }
            }
            // seg1: tgt
            {
                bf16x8 bfr[5];
#pragma unroll
                for (int ct = 0; ct < 5; ct++)
                    bfr[ct] = *(const bf16x8*)(wtb + (size_t)ct * 16 * K3 +
                                               DD + k0 + kk2 * 32);
#pragma unroll
                for (int rt = 0; rt < 8; rt++) {
                    bf16x8 af = *(const bf16x8*)&bufc[sidx2(1, kk2, rt, lane)];
#pragma unroll
                    for (int ct = 0; ct < 5; ct++)
                        acc[ct][rt] = __builtin_amdgcn_mfma_f32_16x16x32_bf16(
                            af, bfr[ct], acc[ct][rt], 0, 0, 0);
                }
            }
            // seg2: |src - tgt| computed in-register
            {
                bf16x8 bfr[5];
#pragma unroll
                for (int ct = 0; ct < 5; ct++)
                    bfr[ct] = *(const bf16x8*)(wtb + (size_t)ct * 16 * K3 +
                                               2 * DD + k0 + kk2 * 32);
#pragma unroll
                for (int rt = 0; rt < 8; rt++) {
                    bf16x8 sF = *(const bf16x8*)&bufc[sidx2(0, kk2, rt, lane)];
                    bf16x8 tF = *(const bf16x8*)&bufc[sidx2(1, kk2, rt, lane)];
                    bf16x8 aF;
#pragma unroll
                    for (int j = 0; j < 8; j++) aF[j] = babsdiff(sF[j], tF[j]);
#pragma unroll
                    for (int ct = 0; ct < 5; ct++)
                        acc[ct][rt] = __builtin_amdgcn_mfma_f32_16x16x32_bf16(
                            aF, bfr[ct], acc[ct][rt], 0, 0, 0);
                }
            }
        }
        __syncthreads();   // waves done with bufc; also drains this wave's DMA
    }

    // ---- epilogue: two 64-row halves ----
#pragma unroll
    for (int h = 0; h < 2; h++) {
        if (h == 1) __syncthreads();
        // phase B: bias + relu -> acts[64][320]. C/D: col=lane&15, row=q*4+reg.
#pragma unroll
        for (int ct = 0; ct < 5; ct++) {
            int col = w * 80 + ct * 16 + ln;
            float bias = (col < 128) ? pb1[col]
                       : (col < 192) ? db1[col - 128]
                                     : rb1[col - 192];
#pragma unroll
            for (int rt4 = 0; rt4 < 4; rt4++)
#pragma unroll
                for (int i = 0; i < 4; i++) {
                    int lrow = rt4 * 16 + q * 4 + i;
                    float v = acc[ct][h * 4 + rt4][i] + bias;
                    acts[lrow][col] = f2b(fmaxf(v, 0.f));
                }
        }
        __syncthreads();

        // C1: relations = relu1_r[64x128] @ rw2 + rb2
        {
            f32x4 rc[4];
#pragma unroll
            for (int rt = 0; rt < 4; rt++) rc[rt] = (f32x4)(0.f);
#pragma unroll
            for (int ks = 0; ks < 4; ks++) {
                bf16x8 bfr = *(const bf16x8*)(rw2T + (w * 16 + ln) * 128 +
                                              ks * 32 + q * 8);
#pragma unroll
                for (int rt = 0; rt < 4; rt++) {
                    bf16x8 afr = *(const bf16x8*)&acts[rt * 16 + ln][192 + ks * 32 + q * 8];
                    rc[rt] = __builtin_amdgcn_mfma_f32_16x16x32_bf16(afr, bfr, rc[rt], 0, 0, 0);
                }
            }
            int col = w * 16 + ln;
            float bias = rb2[col];
            float* rel = out + 2 * (size_t)N;
#pragma unroll
            for (int rt = 0; rt < 4; rt++)
#pragma unroll
                for (int i = 0; i < 4; i++) {
                    int grow = r0 + h * 64 + rt * 16 + q * 4 + i;
                    rel[(size_t)grow * 64 + col] = rc[rt][i] + bias;
                }
        }

        // C2: h2 = relu(relu1_p[64x128] @ pw2 + pb2) -> h2s
        {
            f32x4 pc[4];
#pragma unroll
            for (int rt = 0; rt < 4; rt++) pc[rt] = (f32x4)(0.f);
#pragma unroll
            for (int ks = 0; ks < 4; ks++) {
                bf16x8 bfr = *(const bf16x8*)(pw2T + (w * 16 + ln) * 128 +
                                              ks * 32 + q * 8);
#pragma unroll
                for (int rt = 0; rt < 4; rt++) {
                    bf16x8 afr = *(const bf16x8*)&acts[rt * 16 + ln][0 + ks * 32 + q * 8];
                    pc[rt] = __builtin_amdgcn_mfma_f32_16x16x32_bf16(afr, bfr, pc[rt], 0, 0, 0);
                }
            }
            int col = w * 16 + ln;
            float bias = pb2[col];
#pragma unroll
            for (int rt = 0; rt < 4; rt++)
#pragma unroll
                for (int i = 0; i < 4; i++) {
                    int lrow = rt * 16 + q * 4 + i;
                    h2s[lrow][col] = f2b(fmaxf(pc[rt][i] + bias, 0.f));
                }
        }
        __syncthreads();

        // C3: probs; C4: directions
        if (t < 64) {
            float s = pb3[0];
#pragma unroll 8
            for (int k = 0; k < 64; k++) s += b2f(h2s[t][k]) * pw3[k];
            float pr = 1.f / (1.f + __expf(-s));
            out[r0 + h * 64 + t] = pr;
        } else if (t < 128) {
            int lrow = t - 64;
            float s = db2[0];
#pragma unroll 8
            for (int k = 0; k < 64; k++) s += b2f(acts[lrow][128 + k]) * dw2[k];
            float dir = (1.f / (1.f + __expf(-s))) * 1.57079632679489662f;
            out[(size_t)N + r0 + h * 64 + lrow] = dir;
        }
    }
}

extern "C" void kernel_launch(void* const* d_in, const int* in_sizes, int n_in,
                              void* d_out, int out_size, void* d_ws, size_t ws_size,
                              hipStream_t stream) {
    const float* beliefs = (const float*)d_in[0];
    const int* src = (const int*)d_in[1];
    const int* tgt = (const int*)d_in[2];
    const float* pw1 = (const float*)d_in[3];
    const float* pb1 = (const float*)d_in[4];
    const float* pw2 = (const float*)d_in[5];
    const float* pb2 = (const float*)d_in[6];
    const float* pw3 = (const float*)d_in[7];
    const float* pb3 = (const float*)d_in[8];
    const float* dw1 = (const float*)d_in[9];
    const float* db1 = (const float*)d_in[10];
    const float* dw2 = (const float*)d_in[11];
    const float* db2 = (const float*)d_in[12];
    const float* rw1 = (const float*)d_in[13];
    const float* rb1 = (const float*)d_in[14];
    const float* rw2 = (const float*)d_in[15];
    const float* rb2 = (const float*)d_in[16];

    short* ws = (short*)d_ws;
    short* WT    = ws;
    short* pw2T  = ws + P2T_OFF;
    short* rw2T  = ws + R2T_OFF;
    short* bel16 = ws + BEL_OFF;
    const int N = in_sizes[1];

    const bool useBf = ws_size >= (size_t)(PREP_TOT + BEL_ELEMS) * sizeof(short);
    const int elemN = useBf ? ELEM_TOT : (2 * 64 * 128);
    const int prepBlocks = TRANS_BLOCKS + (elemN + 255) / 256;

    prep_kernel<<<prepBlocks, 256, 0, stream>>>(pw1, dw1, rw1, pw2, rw2,
                                                beliefs, ws);

    if (useBf)
        edge_main<true><<<N / ROWS, 256, 0, stream>>>(
            beliefs, bel16, src, tgt, pb1, db1, rb1, pb2, pw3, pb3,
            dw2, db2, rb2, WT, pw2T, rw2T, (float*)d_out, N);
    else
        edge_main<false><<<N / ROWS, 256, 0, stream>>>(
            beliefs, bel16, src, tgt, pb1, db1, rb1, pb2, pw3, pb3,
            dw2, db2, rb2, WT, pw2T, rw2T, (float*)d_out, N);
}

// Round 10
// 374.536 us; speedup vs baseline: 1.3127x; 1.3127x over previous
//
#include <hip/hip_runtime.h>
#include <hip/hip_bf16.h>

// EdgeProposer: probs/directions/relations heads over gathered belief pairs.
// f32 in / f32 out. Best: R6 196us (128-row, acc160, 2 waves/SIMD, latency-
// bound). Spill law (R5/R7/R8/R9): at acc=160 any added K-loop structure
// spills. R10: acc[5][4]=80 (64-row tile), launch_bounds(256,3) -> 3
// blocks/CU (3 waves/SIMD), LDS double-buffered A-tiles with ONE barrier
// per k0-iter; next-chunk gathers held in 16 regs across the MFMA phase.
// Epilogue split into two column stages to keep aliased LDS <= 35KB.

#define DD 512
#define K3 1536
#define ROWS 64
#define LDACT2 200   // epilogue acts leading dim (shorts)
#define LDH 72
#define BUFSH 12288  // shorts per A-buffer: 3 seg * 2 kk2 * 4 rt * 64 lane * 8

typedef short bf16x8 __attribute__((ext_vector_type(8)));
typedef float f32x4 __attribute__((ext_vector_type(4)));

__device__ inline float b2f(short s) {
    union { float f; unsigned u; } v;
    v.u = ((unsigned)(unsigned short)s) << 16;
    return v.f;
}
__device__ inline short f2b(float f) {   // RNE
    union { float fl; unsigned u; } v;
    v.fl = f;
    unsigned x = v.u;
    unsigned r = x + 0x7fffu + ((x >> 16) & 1u);
    return (short)(r >> 16);
}
__device__ inline short babsdiff(short a, short b) {
    union { float f; unsigned u; } v;
    v.f = b2f(a) - b2f(b);
    return (short)((v.u & 0x7fffffffu) >> 16);
}

// fragment-major: [seg][kk2][rt4][lane][8] (shorts), 64-row tile
__device__ __forceinline__ int sidx64(int seg, int kk2, int rt, int lane) {
    return (((seg * 2 + kk2) * 4 + rt) * 64 + lane) * 8;
}

// ---- workspace layout (shorts) ----
#define WT_ELEMS (320 * 1536)
#define P2T_OFF WT_ELEMS
#define R2T_OFF (WT_ELEMS + 64 * 128)
#define PREP_TOT (WT_ELEMS + 2 * 64 * 128)
#define BEL_ELEMS (8192 * 512)
#define BEL_OFF PREP_TOT

#define TRANS_BLOCKS 480   // (1536/32) * (320/32)
#define ELEM_TOT (2 * 64 * 128 + BEL_ELEMS)

__global__ void prep_kernel(const float* __restrict__ pw1,
                            const float* __restrict__ dw1,
                            const float* __restrict__ rw1,
                            const float* __restrict__ pw2,
                            const float* __restrict__ rw2,
                            const float* __restrict__ beliefs,
                            short* __restrict__ ws) {
    const int bx = blockIdx.x, t = threadIdx.x;
    if (bx < TRANS_BLOCKS) {
        __shared__ short tile[32][33];
        const int tk = (bx / 10) * 32, tn = (bx % 10) * 32;
        const int r = t >> 5, c = t & 31;
#pragma unroll
        for (int p = 0; p < 4; p++) {
            int k = tk + r + p * 8, n = tn + c;
            float v;
            if (n < 128)      v = pw1[k * 128 + n];
            else if (n < 192) v = dw1[k * 64 + (n - 128)];
            else              v = rw1[k * 128 + (n - 192)];
            tile[r + p * 8][c] = f2b(v);
        }
        __syncthreads();
#pragma unroll
        for (int p = 0; p < 4; p++) {
            int nn = tn + r + p * 8, kk = tk + c;
            ws[(size_t)nn * K3 + kk] = tile[c][r + p * 8];
        }
    } else {
        int j = (bx - TRANS_BLOCKS) * 256 + t;
        if (j >= ELEM_TOT) return;
        if (j < 8192) {
            int n = j >> 7, k = j & 127;
            ws[P2T_OFF + j] = f2b(pw2[k * 64 + n]);
        } else if (j < 16384) {
            int jj = j - 8192;
            int n = jj >> 7, k = jj & 127;
            ws[R2T_OFF + jj] = f2b(rw2[k * 64 + n]);
        } else {
            int idx = j - 16384;
            ws[BEL_OFF + idx] = f2b(beliefs[idx]);
        }
    }
}

// ---- main fused kernel: 64 pairs per block, 256 threads, 3 blocks/CU ----
template<bool BF>
__global__ __launch_bounds__(256, 3) void edge_main(
    const float* __restrict__ beliefs, const short* __restrict__ bel16,
    const int* __restrict__ src_idx, const int* __restrict__ tgt_idx,
    const float* __restrict__ pb1, const float* __restrict__ db1,
    const float* __restrict__ rb1,
    const float* __restrict__ pb2, const float* __restrict__ pw3,
    const float* __restrict__ pb3,
    const float* __restrict__ dw2, const float* __restrict__ db2,
    const float* __restrict__ rb2,
    const short* __restrict__ WT, const short* __restrict__ pw2T,
    const short* __restrict__ rw2T,
    float* __restrict__ out, int N)
{
    // two A-buffers (2*24576B); epilogue aliases the front:
    // acts2[64][200] (25600B) + h2s[64][72] (9216B) = 34816B < 49152B.
    __shared__ __align__(16) short smem[2 * BUFSH];
    __shared__ int sIdx[ROWS], tIdx[ROWS];
    short (*acts2)[LDACT2] = (short (*)[LDACT2])smem;
    short (*h2s)[LDH] = (short (*)[LDH])(smem + 64 * LDACT2);

    const int t = threadIdx.x;
    const int r0 = blockIdx.x * ROWS;
    const int w = t >> 6, lane = t & 63, q = lane >> 4, ln = lane & 15;

    if (t < ROWS) sIdx[t] = src_idx[r0 + t] * DD;
    else if (t < 2 * ROWS) tIdx[t - ROWS] = tgt_idx[r0 + t - ROWS] * DD;
    __syncthreads();

    f32x4 acc[5][4];
#pragma unroll
    for (int ct = 0; ct < 5; ct++)
#pragma unroll
        for (int rt = 0; rt < 4; rt++) acc[ct][rt] = (f32x4)(0.f);

    // staging role: thread t covers row m = t&63, k-quarter kk = t>>2... (t>>6)
    // 16 k-elems of BOTH sides -> held 16 regs (BF) / 32 regs (f32).
    const int m = t & 63, kk = t >> 6;
    const int rt4w = m >> 4, lnw = m & 15;
    const int kk2w = kk >> 1, qw = (kk & 1) * 2;   // writes q-slots qw, qw+1
    const int srow = sIdx[m], trow = tIdx[m];

    bf16x8 hS[2], hT[2];
    float4 fS[4], fT[4];

    const short* wtb = WT + (size_t)(w * 80 + ln) * K3 + q * 8;

#define ISSUE(kc)                                                             \
    do {                                                                      \
        if constexpr (BF) {                                                   \
            const bf16x8* sp_ = (const bf16x8*)(bel16 + srow + (kc) + kk * 16);\
            const bf16x8* tp_ = (const bf16x8*)(bel16 + trow + (kc) + kk * 16);\
            hS[0] = sp_[0]; hS[1] = sp_[1];                                   \
            hT[0] = tp_[0]; hT[1] = tp_[1];                                   \
        } else {                                                              \
            const float4* sp_ = (const float4*)(beliefs + srow + (kc) + kk * 16);\
            const float4* tp_ = (const float4*)(beliefs + trow + (kc) + kk * 16);\
            fS[0]=sp_[0]; fS[1]=sp_[1]; fS[2]=sp_[2]; fS[3]=sp_[3];           \
            fT[0]=tp_[0]; fT[1]=tp_[1]; fT[2]=tp_[2]; fT[3]=tp_[3];           \
        }                                                                     \
    } while (0)

#define CONSUME(buf)                                                          \
    do {                                                                      \
        bf16x8 sb[2], tb[2], ab[2];                                           \
        if constexpr (BF) {                                                   \
            sb[0] = hS[0]; sb[1] = hS[1]; tb[0] = hT[0]; tb[1] = hT[1];       \
        } else {                                                              \
            _Pragma("unroll")                                                 \
            for (int i = 0; i < 2; i++) {                                     \
                float4 a0 = fS[i*2], a1 = fS[i*2+1];                          \
                float4 b0 = fT[i*2], b1 = fT[i*2+1];                          \
                float sv[8] = {a0.x,a0.y,a0.z,a0.w,a1.x,a1.y,a1.z,a1.w};      \
                float tv[8] = {b0.x,b0.y,b0.z,b0.w,b1.x,b1.y,b1.z,b1.w};      \
                _Pragma("unroll")                                             \
                for (int j = 0; j < 8; j++) {                                 \
                    sb[i][j] = f2b(sv[j]); tb[i][j] = f2b(tv[j]);             \
                }                                                             \
            }                                                                 \
        }                                                                     \
        _Pragma("unroll")                                                     \
        for (int i = 0; i < 2; i++) {                                         \
            _Pragma("unroll")                                                 \
            for (int j = 0; j < 8; j++) ab[i][j] = babsdiff(sb[i][j], tb[i][j]);\
            int lp = (qw + i) * 16 + lnw;                                     \
            short* bb = smem + (buf) * BUFSH;                                 \
            *(bf16x8*)&bb[sidx64(0, kk2w, rt4w, lp)] = sb[i];                 \
            *(bf16x8*)&bb[sidx64(1, kk2w, rt4w, lp)] = tb[i];                 \
            *(bf16x8*)&bb[sidx64(2, kk2w, rt4w, lp)] = ab[i];                 \
        }                                                                     \
    } while (0)

    ISSUE(0);
    CONSUME(0);
    __syncthreads();

    for (int k0 = 0; k0 < DD; k0 += 64) {
        const int cur = (k0 >> 6) & 1;
        if (k0 + 64 < DD) ISSUE(k0 + 64);

        const short* bufc = smem + cur * BUFSH;
#pragma unroll
        for (int kk2 = 0; kk2 < 2; kk2++) {
#pragma unroll
            for (int seg = 0; seg < 3; seg++) {
                bf16x8 bfr[5];
#pragma unroll
                for (int ct = 0; ct < 5; ct++)
                    bfr[ct] = *(const bf16x8*)(wtb + (size_t)ct * 16 * K3 +
                                               seg * DD + k0 + kk2 * 32);
#pragma unroll
                for (int rt = 0; rt < 4; rt++) {
                    bf16x8 af = *(const bf16x8*)&bufc[sidx64(seg, kk2, rt, lane)];
#pragma unroll
                    for (int ct = 0; ct < 5; ct++)
                        acc[ct][rt] = __builtin_amdgcn_mfma_f32_16x16x32_bf16(
                            af, bfr[ct], acc[ct][rt], 0, 0, 0);
                }
            }
        }
        if (k0 + 64 < DD) CONSUME(cur ^ 1);
        __syncthreads();
    }

    // ---- epilogue, col-split stages. C/D: col=lane&15, row=q*4+reg ----
    // stage A: tiles g = w*5+ct with 16g < 192 (p + d columns)
#pragma unroll
    for (int ct = 0; ct < 5; ct++) {
        int col = w * 80 + ct * 16 + ln;
        if (col < 192) {
            float bias = (col < 128) ? pb1[col] : db1[col - 128];
#pragma unroll
            for (int rt = 0; rt < 4; rt++)
#pragma unroll
                for (int i = 0; i < 4; i++) {
                    int lrow = rt * 16 + q * 4 + i;
                    acts2[lrow][col] = f2b(fmaxf(acc[ct][rt][i] + bias, 0.f));
                }
        }
    }
    __syncthreads();

    // C2: h2 = relu(acts2[:,0:128] @ pw2 + pb2) -> h2s
    {
        f32x4 pc[4];
#pragma unroll
        for (int rt = 0; rt < 4; rt++) pc[rt] = (f32x4)(0.f);
#pragma unroll
        for (int ks = 0; ks < 4; ks++) {
            bf16x8 bfr = *(const bf16x8*)(pw2T + (w * 16 + ln) * 128 +
                                          ks * 32 + q * 8);
#pragma unroll
            for (int rt = 0; rt < 4; rt++) {
                bf16x8 afr = *(const bf16x8*)&acts2[rt * 16 + ln][ks * 32 + q * 8];
                pc[rt] = __builtin_amdgcn_mfma_f32_16x16x32_bf16(afr, bfr, pc[rt], 0, 0, 0);
            }
        }
        int col = w * 16 + ln;
        float bias = pb2[col];
#pragma unroll
        for (int rt = 0; rt < 4; rt++)
#pragma unroll
            for (int i = 0; i < 4; i++) {
                int lrow = rt * 16 + q * 4 + i;
                h2s[lrow][col] = f2b(fmaxf(pc[rt][i] + bias, 0.f));
            }
    }
    // C4: directions from acts2[:,128:192]
    if (t >= 64 && t < 128) {
        int lrow = t - 64;
        float s = db2[0];
#pragma unroll 8
        for (int k = 0; k < 64; k++) s += b2f(acts2[lrow][128 + k]) * dw2[k];
        float dir = (1.f / (1.f + __expf(-s))) * 1.57079632679489662f;
        out[(size_t)N + r0 + lrow] = dir;
    }
    __syncthreads();

    // C3: probs from h2s; stage B: r columns into acts2[:,0:128]
    if (t < 64) {
        float s = pb3[0];
#pragma unroll 8
        for (int k = 0; k < 64; k++) s += b2f(h2s[t][k]) * pw3[k];
        out[r0 + t] = 1.f / (1.f + __expf(-s));
    }
#pragma unroll
    for (int ct = 0; ct < 5; ct++) {
        int col = w * 80 + ct * 16 + ln;
        if (col >= 192) {
            float bias = rb1[col - 192];
#pragma unroll
            for (int rt = 0; rt < 4; rt++)
#pragma unroll
                for (int i = 0; i < 4; i++) {
                    int lrow = rt * 16 + q * 4 + i;
                    acts2[lrow][col - 192] = f2b(fmaxf(acc[ct][rt][i] + bias, 0.f));
                }
        }
    }
    __syncthreads();

    // C1: relations = acts2(r) @ rw2 + rb2
    {
        f32x4 rc[4];
#pragma unroll
        for (int rt = 0; rt < 4; rt++) rc[rt] = (f32x4)(0.f);
#pragma unroll
        for (int ks = 0; ks < 4; ks++) {
            bf16x8 bfr = *(const bf16x8*)(rw2T + (w * 16 + ln) * 128 +
                                          ks * 32 + q * 8);
#pragma unroll
            for (int rt = 0; rt < 4; rt++) {
                bf16x8 afr = *(const bf16x8*)&acts2[rt * 16 + ln][ks * 32 + q * 8];
                rc[rt] = __builtin_amdgcn_mfma_f32_16x16x32_bf16(afr, bfr, rc[rt], 0, 0, 0);
            }
        }
        int col = w * 16 + ln;
        float bias = rb2[col];
        float* rel = out + 2 * (size_t)N;
#pragma unroll
        for (int rt = 0; rt < 4; rt++)
#pragma unroll
            for (int i = 0; i < 4; i++) {
                int grow = r0 + rt * 16 + q * 4 + i;
                rel[(size_t)grow * 64 + col] = rc[rt][i] + bias;
            }
    }
}

extern "C" void kernel_launch(void* const* d_in, const int* in_sizes, int n_in,
                              void* d_out, int out_size, void* d_ws, size_t ws_size,
                              hipStream_t stream) {
    const float* beliefs = (const float*)d_in[0];
    const int* src = (const int*)d_in[1];
    const int* tgt = (const int*)d_in[2];
    const float* pw1 = (const float*)d_in[3];
    const float* pb1 = (const float*)d_in[4];
    const float* pw2 = (const float*)d_in[5];
    const float* pb2 = (const float*)d_in[6];
    const float* pw3 = (const float*)d_in[7];
    const float* pb3 = (const float*)d_in[8];
    const float* dw1 = (const float*)d_in[9];
    const float* db1 = (const float*)d_in[10];
    const float* dw2 = (const float*)d_in[11];
    const float* db2 = (const float*)d_in[12];
    const float* rw1 = (const float*)d_in[13];
    const float* rb1 = (const float*)d_in[14];
    const float* rw2 = (const float*)d_in[15];
    const float* rb2 = (const float*)d_in[16];

    short* ws = (short*)d_ws;
    short* WT    = ws;
    short* pw2T  = ws + P2T_OFF;
    short* rw2T  = ws + R2T_OFF;
    short* bel16 = ws + BEL_OFF;
    const int N = in_sizes[1];

    const bool useBf = ws_size >= (size_t)(PREP_TOT + BEL_ELEMS) * sizeof(short);
    const int elemN = useBf ? ELEM_TOT : (2 * 64 * 128);
    const int prepBlocks = TRANS_BLOCKS + (elemN + 255) / 256;

    prep_kernel<<<prepBlocks, 256, 0, stream>>>(pw1, dw1, rw1, pw2, rw2,
                                                beliefs, ws);

    if (useBf)
        edge_main<true><<<N / ROWS, 256, 0, stream>>>(
            beliefs, bel16, src, tgt, pb1, db1, rb1, pb2, pw3, pb3,
            dw2, db2, rb2, WT, pw2T, rw2T, (float*)d_out, N);
    else
        edge_main<false><<<N / ROWS, 256, 0, stream>>>(
            beliefs, bel16, src, tgt, pb1, db1, rb1, pb2, pw3, pb3,
            dw2, db2, rb2, WT, pw2T, rw2T, (float*)d_out, N);
}